// Round 6
// baseline (199.705 us; speedup 1.0000x reference)
//
#include <hip/hip_runtime.h>

#define VOCAB 50257
#define EMBED 512
#define HID   512
#define B     128
#define SRC   128

typedef __attribute__((ext_vector_type(8))) short short8;
typedef __attribute__((ext_vector_type(4))) float f32x4;

// f32 -> bf16 (round-to-nearest-even), result in low 16 bits
__device__ __forceinline__ unsigned f2bf(float x) {
    unsigned u = __builtin_bit_cast(unsigned, x);
    return (u + 0x7fffu + ((u >> 16) & 1u)) >> 16;
}
__device__ __forceinline__ unsigned pk2(float lo, float hi) {
    return f2bf(lo) | (f2bf(hi) << 16);
}
__device__ __forceinline__ uint4 pk8(const float* p) {
    uint4 r;
    r.x = pk2(p[0], p[1]); r.y = pk2(p[2], p[3]);
    r.z = pk2(p[4], p[5]); r.w = pk2(p[6], p[7]);
    return r;
}
__device__ __forceinline__ uint4 pk8v(float4 a, float4 b) {
    uint4 r;
    r.x = pk2(a.x, a.y); r.y = pk2(a.z, a.w);
    r.z = pk2(b.x, b.y); r.w = pk2(b.z, b.w);
    return r;
}
__device__ __forceinline__ void gll16(const void* g, void* l) {
    __builtin_amdgcn_global_load_lds(
        (const __attribute__((address_space(1))) void*)g,
        (__attribute__((address_space(3))) void*)l, 16, 0, 0);
}

// Fragment-packed A layout (bf16, mfma_f32_16x16x32_bf16 A-operand order):
// uint4 index = ((kc*8 + mt)*4 + ksl)*64 + kg*16 + (row&15)
//   row = mt*16 + (row&15), k = kc*128 + ksl*32 + kg*8 + j (j=0..7)
// Each 128-k chunk (kc) is a contiguous 2048-uint4 (32KB) block.

// ---------------------------------------------------------------------------
// K1: pack rnn_in = [emb(x[b]) | ctxv[b]]  (K=1024) and h0[b]  (K=512)
// ---------------------------------------------------------------------------
__global__ void k_embed_pack(const int* __restrict__ x, const float* __restrict__ ctxv,
                             const float* __restrict__ emb, const float* __restrict__ h0,
                             uint4* __restrict__ apk_rnn, uint4* __restrict__ apk_h0) {
    __shared__ float buf[1024];
    __shared__ float hbuf[512];
    const int b = blockIdx.x, t = threadIdx.x;
    const int row = x[b];
    if (t < 128) {
        ((float4*)buf)[t]  = ((const float4*)(emb + (size_t)row * EMBED))[t];
        ((float4*)hbuf)[t] = ((const float4*)(h0 + (size_t)b * HID))[t];
    } else {
        ((float4*)buf)[t] = ((const float4*)(ctxv + (size_t)b * HID))[t - 128];
    }
    __syncthreads();
    const int mt = b >> 4, lb = b & 15;
    if (t < 128) {                       // rnn frag t (K=1024)
        int kc = t >> 4, ksl = (t >> 2) & 3, kg = t & 3;
        apk_rnn[((kc * 8 + mt) * 4 + ksl) * 64 + kg * 16 + lb] = pk8(&buf[t * 8]);
    } else if (t < 192) {                // h0 frag (K=512)
        int i = t - 128;
        int kc = i >> 4, ksl = (i >> 2) & 3, kg = i & 3;
        apk_h0[((kc * 8 + mt) * 4 + ksl) * 64 + kg * 16 + lb] = pk8(&hbuf[i * 8]);
    }
}

// ---------------------------------------------------------------------------
// K2: LDS-free MFMA GEMM, 1 wave per block, 16 cols/block, all 128 m.
// ---------------------------------------------------------------------------
template <int N, int K, int ACT, int HASB, int PACK>
__global__ __launch_bounds__(64, 4) void k_gemm_direct(
        const uint4* __restrict__ apk, const float* __restrict__ W,
        const float* __restrict__ bias, float* __restrict__ C,
        uint4* __restrict__ apk_out) {
    const int lane = threadIdx.x;
    const int n0 = blockIdx.x * 16;
    const int ncol = n0 + (lane & 15);
    const int nc = ncol < N ? ncol : N - 1;
    const int kg = lane >> 4;
    f32x4 acc[8];
#pragma unroll
    for (int mt = 0; mt < 8; ++mt) acc[mt] = (f32x4)0.f;
    const float* wb = W + (size_t)nc * K + kg * 8;
#pragma unroll
    for (int kc = 0; kc < K / 128; ++kc) {
#pragma unroll
        for (int ksl = 0; ksl < 4; ++ksl) {
            const float* wp = wb + kc * 128 + ksl * 32;
            float4 w0 = *(const float4*)wp;
            float4 w1 = *(const float4*)(wp + 4);
            short8 bf = __builtin_bit_cast(short8, pk8v(w0, w1));
            const uint4* ap = apk + ((size_t)kc * 32 + ksl) * 64 + lane;
#pragma unroll
            for (int mt = 0; mt < 8; ++mt) {
                short8 af = __builtin_bit_cast(short8, ap[mt * 256]);
                acc[mt] = __builtin_amdgcn_mfma_f32_16x16x32_bf16(af, bf, acc[mt], 0, 0, 0);
            }
        }
    }
    const int r0 = (lane >> 4) * 4;
    float bb = (HASB && ncol < N) ? bias[ncol] : 0.f;
    if constexpr (!PACK) {
        if (ncol < N) {
#pragma unroll
            for (int mt = 0; mt < 8; ++mt) {
#pragma unroll
                for (int j = 0; j < 4; ++j) {
                    float v = acc[mt][j] + bb;
                    if (ACT) v = tanhf(v);
                    C[(size_t)(mt * 16 + r0 + j) * N + ncol] = v;
                }
            }
        }
    } else {
        __shared__ float pt[128][17];
#pragma unroll
        for (int mt = 0; mt < 8; ++mt) {
#pragma unroll
            for (int j = 0; j < 4; ++j) {
                float v = acc[mt][j] + bb;
                if (ACT) v = tanhf(v);
                C[(size_t)(mt * 16 + r0 + j) * N + ncol] = v;
                pt[mt * 16 + r0 + j][lane & 15] = v;
            }
        }
        __syncthreads();
#pragma unroll
        for (int i = 0; i < 4; ++i) {
            int fid = i * 64 + lane;       // 256 frags: (row r, half hf)
            int r = fid >> 1, hf = fid & 1;
            int k0 = n0 + hf * 8;          // global k of first elem
            int kc = k0 >> 7, ksl = (k0 >> 5) & 3, kg2 = (k0 >> 3) & 3;
            apk_out[((kc * 8 + (r >> 4)) * 4 + ksl) * 64 + kg2 * 16 + (r & 15)] =
                pk8(&pt[r][hf * 8]);
        }
    }
}

// ---------------------------------------------------------------------------
// K3: GRU gate combine (r,z,n) + pack h fragments (K=512)
// ---------------------------------------------------------------------------
__global__ void k_gru(const float* __restrict__ gi, const float* __restrict__ gh,
                      const float* __restrict__ h0, float* __restrict__ h,
                      uint4* __restrict__ apk_h) {
    __shared__ float hsh[256];
    const int t = threadIdx.x;
    const int idx = blockIdx.x * 256 + t;
    const int b = blockIdx.x >> 1, half = blockIdx.x & 1;
    const int j = half * 256 + t;
    const float* gib = gi + (size_t)b * 1536;
    const float* ghb = gh + (size_t)b * 1536;
    float ir = gib[j], iz = gib[512 + j], inn = gib[1024 + j];
    float hr = ghb[j], hz = ghb[512 + j], hn = ghb[1024 + j];
    float r = 1.f / (1.f + expf(-(ir + hr)));
    float z = 1.f / (1.f + expf(-(iz + hz)));
    float nn = tanhf(inn + r * hn);
    float hv = (1.f - z) * nn + z * h0[idx];
    h[idx] = hv;
    hsh[t] = hv;
    __syncthreads();
    if (t < 32) {
        int k0 = half * 256 + t * 8;
        int kc = k0 >> 7, ksl = (k0 >> 5) & 3, kg = (k0 >> 3) & 3;
        apk_h[((kc * 8 + (b >> 4)) * 4 + ksl) * 64 + kg * 16 + (b & 15)] = pk8(&hsh[t * 8]);
    }
}

// ---------------------------------------------------------------------------
// K4: attention (512 threads)
// ---------------------------------------------------------------------------
__global__ __launch_bounds__(512) void k_attn(const float* __restrict__ enc,
        const float* __restrict__ q, const int* __restrict__ lens,
        const float* __restrict__ h, float* __restrict__ a_out,
        uint4* __restrict__ apk_cat) {
    __shared__ float qs[512];
    __shared__ float red[128];
    __shared__ float aw[128];
    __shared__ float catsh[1024];
    const int b = blockIdx.x, t = threadIdx.x;
    qs[t] = q[(size_t)b * 512 + t];
    __syncthreads();
    const int srow = t >> 2, part = t & 3;
    const float* ep = enc + ((size_t)b * SRC + srow) * 512 + part * 128;
    float s = 0.f;
#pragma unroll
    for (int k4 = 0; k4 < 32; ++k4) {
        float4 e = ((const float4*)ep)[k4];
        float4 qq = *(const float4*)&qs[part * 128 + k4 * 4];
        s = fmaf(e.x, qq.x, fmaf(e.y, qq.y, fmaf(e.z, qq.z, fmaf(e.w, qq.w, s))));
    }
    s += __shfl_xor(s, 1);
    s += __shfl_xor(s, 2);
    if (part == 0) {
        int len = lens[b];
        float val = (srow < len) ? s : 0.f;
        if (val == 0.f) val = -1e10f;   // replicate ref's where(masked==0,-1e10)
        red[srow] = val;
        aw[srow] = val;
    }
    __syncthreads();
    for (int off = 64; off > 0; off >>= 1) {          // max tree
        if (t < off) red[t] = fmaxf(red[t], red[t + off]);
        __syncthreads();
    }
    float mx = red[0];
    __syncthreads();
    if (t < 128) { float e = expf(aw[t] - mx); aw[t] = e; red[t] = e; }
    __syncthreads();
    for (int off = 64; off > 0; off >>= 1) {          // sum tree
        if (t < off) red[t] += red[t + off];
        __syncthreads();
    }
    float denom = red[0];
    if (t < 128) {
        float av = aw[t] / denom;
        aw[t] = av;
        a_out[(size_t)t * B + b] = av;                // layout [S][B]
    }
    __syncthreads();
    float a0 = 0.f;
    const float* e2 = enc + (size_t)b * (SRC * 512) + t;
#pragma unroll 4
    for (int s2 = 0; s2 < SRC; ++s2) a0 = fmaf(aw[s2], e2[(size_t)s2 * 512], a0);
    catsh[t] = a0;
    catsh[512 + t] = h[(size_t)b * 512 + t];
    __syncthreads();
    if (t < 128) {                                    // pack cat frag (K=1024)
        int kc = t >> 4, ksl = (t >> 2) & 3, kg = t & 3;
        apk_cat[((kc * 8 + (b >> 4)) * 4 + ksl) * 64 + kg * 16 + (b & 15)] =
            pk8(&catsh[t * 8]);
    }
}

// ---------------------------------------------------------------------------
// K5: fc1 GEMM v2: A via global_load_lds (frag-packed), W streamed COALESCED
// (octet o = row o>>4, k-octet o&15 -> 512B contiguous per 16 lanes) ->
// bf16 pack -> double-buffered swizzled LDS frag buffer. Fused LSE partials.
// ---------------------------------------------------------------------------
__device__ __forceinline__ void fc1_loadW(const float* __restrict__ W, int n0,
                                          int kc, int t, float4* wr) {
    const float4* W4 = (const float4*)W;
    const size_t gmax = (size_t)VOCAB * 128 - 1;     // last valid float4 idx
#pragma unroll
    for (int ii = 0; ii < 4; ++ii) {
        int o = ii * 256 + t;            // octet: row r = o>>4, k-octet oo = o&15
        int r = o >> 4, oo = o & 15;
        size_t g = (size_t)(n0 + r) * 128 + (size_t)kc * 32 + (size_t)oo * 2;
        size_t g0 = g < gmax ? g : gmax;
        size_t g1 = (g + 1) < gmax ? (g + 1) : gmax;
        wr[2 * ii]     = W4[g0];
        wr[2 * ii + 1] = W4[g1];
    }
}
__device__ __forceinline__ void fc1_packW(const float4* wr, int t,
                                          uint4* __restrict__ wbuf) {
#pragma unroll
    for (int ii = 0; ii < 4; ++ii) {
        int o = ii * 256 + t;            // octet index in 64x128 chunk
        int r = o >> 4, oo = o & 15;     // r = col-row (0..63), oo = k-octet
        int fidx = ((r >> 4) * 4 + (oo >> 2)) * 64 + (oo & 3) * 16 + (r & 15);
        int sidx = fidx ^ ((fidx >> 6) & 7);     // symmetric XOR swizzle
        wbuf[sidx] = pk8v(wr[2 * ii], wr[2 * ii + 1]);
    }
}

template <int N, int K>   // N=VOCAB, K=512
__global__ __launch_bounds__(256, 2) void k_fc1b(
        const uint4* __restrict__ apk, const float* __restrict__ W,
        const float* __restrict__ bias, float* __restrict__ C,
        float2* __restrict__ pout) {
    __shared__ uint4 As[2048];        // 32KB: one 128-k chunk of packed A
    __shared__ uint4 Wl[2][1024];     // 2 x 16KB packed W chunk (frag order)
    __shared__ float pm4[4][128];
    __shared__ float ps4[4][128];
    const int tid = threadIdx.x, lane = tid & 63, wv = tid >> 6;
    const int bid = blockIdx.x;
    const int n0 = bid * 64;
    const int ncol = n0 + wv * 16 + (lane & 15);
    const bool valid = ncol < N;
    f32x4 acc[8];
#pragma unroll
    for (int mt = 0; mt < 8; ++mt) acc[mt] = (f32x4)0.f;

    float4 wr[8];
    fc1_loadW(W, n0, 0, tid, wr);
#pragma unroll
    for (int it = 0; it < 8; ++it)     // stage A chunk 0
        gll16(apk + it * 256 + wv * 64 + lane, As + it * 256 + wv * 64);
    fc1_packW(wr, tid, Wl[0]);
    __syncthreads();                   // A(0) DMA + W(0) pack complete

#pragma unroll
    for (int kc = 0; kc < 4; ++kc) {
        if (kc < 3) fc1_loadW(W, n0, kc + 1, tid, wr);   // prefetch next W
        const int cur = kc & 1;
#pragma unroll
        for (int ksl = 0; ksl < 4; ++ksl) {
            const int fb = wv * 4 + ksl;
            short8 bf = __builtin_bit_cast(short8, Wl[cur][fb * 64 + (lane ^ (fb & 7))]);
#pragma unroll
            for (int mt = 0; mt < 8; ++mt) {
                short8 af = __builtin_bit_cast(short8, As[(mt * 4 + ksl) * 64 + lane]);
                acc[mt] = __builtin_amdgcn_mfma_f32_16x16x32_bf16(af, bf, acc[mt], 0, 0, 0);
            }
        }
        __syncthreads();               // everyone done reading As / Wl[cur]
        if (kc < 3) {
#pragma unroll
            for (int it = 0; it < 8; ++it)
                gll16(apk + (kc + 1) * 2048 + it * 256 + wv * 64 + lane,
                      As + it * 256 + wv * 64);
            fc1_packW(wr, tid, Wl[cur ^ 1]);
            __syncthreads();           // next A DMA + W pack complete
        }
    }

    const int kg = lane >> 4;
    float bb = bias[valid ? ncol : 0];
#pragma unroll
    for (int mt = 0; mt < 8; ++mt) {
#pragma unroll
        for (int j = 0; j < 4; ++j) {
            float v = acc[mt][j] + bb;
            int row = mt * 16 + kg * 4 + j;
            if (valid) C[(size_t)row * N + ncol] = v;
            if (pout) {
                float val = valid ? v : -1e30f;
                float m16 = val;
                m16 = fmaxf(m16, __shfl_xor(m16, 1));
                m16 = fmaxf(m16, __shfl_xor(m16, 2));
                m16 = fmaxf(m16, __shfl_xor(m16, 4));
                m16 = fmaxf(m16, __shfl_xor(m16, 8));
                float e = valid ? __expf(val - m16) : 0.f;
                e += __shfl_xor(e, 1);
                e += __shfl_xor(e, 2);
                e += __shfl_xor(e, 4);
                e += __shfl_xor(e, 8);
                if ((lane & 15) == 0) { pm4[wv][row] = m16; ps4[wv][row] = e; }
            }
        }
    }
    if (pout) {
        __syncthreads();
        if (tid < 128) {
            float m = pm4[0][tid], s = ps4[0][tid];
#pragma unroll
            for (int w = 1; w < 4; ++w) {
                float m2 = pm4[w][tid], s2 = ps4[w][tid];
                float mm = fmaxf(m, m2);
                s = s * __expf(m - mm) + s2 * __expf(m2 - mm);
                m = mm;
            }
            pout[(size_t)tid * gridDim.x + bid] = make_float2(m, s);
        }
    }
}

// ---------------------------------------------------------------------------
// K6a: merge per-block LSE partials -> L[row]
// ---------------------------------------------------------------------------
__global__ __launch_bounds__(256) void k_lse_final(const float2* __restrict__ pout,
                                                   float* __restrict__ L, int nblk) {
    const int row = blockIdx.x, t = threadIdx.x;
    float m = -1e30f, s = 0.f;
    for (int i = t; i < nblk; i += 256) {
        float2 p = pout[(size_t)row * nblk + i];
        float mm = fmaxf(m, p.x);
        s = s * __expf(m - mm) + p.y * __expf(p.x - mm);
        m = mm;
    }
    __shared__ float sm[256], ss[256];
    sm[t] = m; ss[t] = s; __syncthreads();
    for (int off = 128; off > 0; off >>= 1) {
        if (t < off) {
            float m2 = sm[t + off], s2 = ss[t + off];
            float mm = fmaxf(sm[t], m2);
            ss[t] = ss[t] * __expf(sm[t] - mm) + s2 * __expf(m2 - mm);
            sm[t] = mm;
        }
        __syncthreads();
    }
    if (t == 0) L[row] = sm[0] + logf(ss[0]);
}

// ---------------------------------------------------------------------------
// K6b: log_probs = logits - L[b]  (in place), full-machine grid
// ---------------------------------------------------------------------------
__global__ __launch_bounds__(512) void k_lsub(float* __restrict__ logits,
                                              const float* __restrict__ L) {
    const int b = blockIdx.y;
    const float l = L[b];
    float* row = logits + (size_t)b * VOCAB;
    int c0 = (blockIdx.x * 512 + threadIdx.x) * 4;
    if (c0 + 4 <= VOCAB) {
        float4 x = *(float4*)(row + c0);
        x.x -= l; x.y -= l; x.z -= l; x.w -= l;
        *(float4*)(row + c0) = x;
    } else {
        for (int c = c0; c < VOCAB; ++c) row[c] -= l;
    }
}

// ---------------------------------------------------------------------------
// K6-fallback: fused log-softmax (online LSE + in-place subtract)
// ---------------------------------------------------------------------------
__global__ __launch_bounds__(1024) void k_lse_sub(float* __restrict__ logits) {
    const int b = blockIdx.x, t = threadIdx.x;
    float* row = logits + (size_t)b * VOCAB;
    const int N4 = VOCAB >> 2;
    float m = -1e30f, s = 0.f;
    for (int i = t; i < N4; i += 1024) {
        float4 x = ((const float4*)row)[i];
        float xs[4] = {x.x, x.y, x.z, x.w};
#pragma unroll
        for (int j = 0; j < 4; ++j) {
            float v = xs[j];
            if (v > m) { s = s * __expf(m - v) + 1.f; m = v; }
            else        s += __expf(v - m);
        }
    }
    if (t == 0) {
        float v = row[VOCAB - 1];
        if (v > m) { s = s * __expf(m - v) + 1.f; m = v; }
        else        s += __expf(v - m);
    }
    __shared__ float sm[1024], ss[1024];
    sm[t] = m; ss[t] = s;
    __syncthreads();
    for (int off = 512; off > 0; off >>= 1) {
        if (t < off) {
            float m2 = sm[t + off], s2 = ss[t + off];
            float mm = fmaxf(sm[t], m2);
            ss[t] = ss[t] * __expf(sm[t] - mm) + s2 * __expf(m2 - mm);
            sm[t] = mm;
        }
        __syncthreads();
    }
    __shared__ float Lsh;
    if (t == 0) Lsh = sm[0] + logf(ss[0]);
    __syncthreads();
    float L = Lsh;
    for (int i = t; i < N4; i += 1024) {
        float4 x = ((const float4*)row)[i];
        x.x -= L; x.y -= L; x.z -= L; x.w -= L;
        ((float4*)row)[i] = x;
    }
    if (t == 0) row[VOCAB - 1] -= L;
}

// ---------------------------------------------------------------------------
extern "C" void kernel_launch(void* const* d_in, const int* in_sizes, int n_in,
                              void* d_out, int out_size, void* d_ws, size_t ws_size,
                              hipStream_t stream) {
    const int*   x    = (const int*)d_in[0];
    const float* h0   = (const float*)d_in[1];   // decoder_hidden [1,B,H]
    const int*   lens = (const int*)d_in[2];
    const float* enc  = (const float*)d_in[3];   // [B,SRC,H]
    const float* ctxv = (const float*)d_in[4];   // [B,H]
    const float* emb  = (const float*)d_in[5];   // [V,E]
    const float* wih  = (const float*)d_in[6];   // [1536,1024]
    const float* whh  = (const float*)d_in[7];   // [1536,512]
    const float* bih  = (const float*)d_in[8];
    const float* bhh  = (const float*)d_in[9];
    const float* Wa   = (const float*)d_in[10];  // [512,512]
    const float* Wc   = (const float*)d_in[11];  // [512,1024]
    const float* fc1w = (const float*)d_in[12];  // [V,512]
    const float* fc1b = (const float*)d_in[13];

    float* out     = (float*)d_out;
    float* outLogp = out;                                  // [B][VOCAB]
    float* outHid  = out + (size_t)B * VOCAB;              // [B][HID]
    float* outA    = outHid + (size_t)B * HID;             // [SRC][B]
    float* outCtx  = outA + (size_t)SRC * B;               // [B][HID]

    // scratch inside the not-yet-written log_probs region (6.43M floats)
    float* gi = outLogp;                                   // [B][1536]
    float* gh = gi + B * 1536;                             // [B][1536]
    float* q  = gh + B * 1536;                             // [B][512]
    uint4* apk_rnn = (uint4*)(q + B * HID);                // 16384 u4 (K=1024)
    uint4* apk_h0  = apk_rnn + 16384;                      // 8192  u4 (K=512)
    uint4* apk_h   = apk_h0 + 8192;                        // 8192  u4 (K=512)
    uint4* apk_cat = apk_h + 8192;                         // 16384 u4 (K=1024)

    const int NBLK = (VOCAB + 63) / 64;                    // 786
    uint4*  apk_ctx = (uint4*)d_ws;                        // 128KB (survives fc1)
    size_t  off_pout = 131072;
    size_t  off_L    = off_pout + (size_t)B * NBLK * sizeof(float2);
    bool bigws = ws_size >= off_L + 512;
    float2* pout = bigws ? (float2*)((char*)d_ws + off_pout) : nullptr;
    float*  Lb   = bigws ? (float*)((char*)d_ws + off_L) : nullptr;

    k_embed_pack<<<dim3(B), dim3(256), 0, stream>>>(x, ctxv, emb, h0, apk_rnn, apk_h0);
    k_gemm_direct<1536, 1024, 0, 1, 0><<<dim3(96), dim3(64), 0, stream>>>(
        apk_rnn, wih, bih, gi, nullptr);
    k_gemm_direct<1536, 512, 0, 1, 0><<<dim3(96), dim3(64), 0, stream>>>(
        apk_h0, whh, bhh, gh, nullptr);
    k_gru<<<dim3(256), dim3(256), 0, stream>>>(gi, gh, h0, outHid, apk_h);
    k_gemm_direct<512, 512, 0, 0, 0><<<dim3(32), dim3(64), 0, stream>>>(
        apk_h, Wa, nullptr, q, nullptr);
    k_attn<<<dim3(B), dim3(512), 0, stream>>>(enc, q, lens, outHid, outA, apk_cat);
    k_gemm_direct<512, 1024, 1, 0, 1><<<dim3(32), dim3(64), 0, stream>>>(
        apk_cat, Wc, nullptr, outCtx, apk_ctx);
    k_fc1b<VOCAB, 512><<<dim3(NBLK), dim3(256), 0, stream>>>(
        apk_ctx, fc1w, fc1b, outLogp, pout);
    if (bigws) {
        k_lse_final<<<dim3(B), dim3(256), 0, stream>>>(pout, Lb, NBLK);
        k_lsub<<<dim3(25, B), dim3(512), 0, stream>>>(outLogp, Lb);
    } else {
        k_lse_sub<<<dim3(B), dim3(1024), 0, stream>>>(outLogp);
    }
}

// Round 7
// 122.719 us; speedup vs baseline: 1.6273x; 1.6273x over previous
//
#include <hip/hip_runtime.h>

#define VOCAB 50257
#define EMBED 512
#define HID   512
#define B     128
#define SRC   128
#define NT393 393   // fc1 column tiles of 128

typedef __attribute__((ext_vector_type(8))) short short8;
typedef __attribute__((ext_vector_type(4))) float f32x4;

// f32 -> bf16 (round-to-nearest-even), result in low 16 bits
__device__ __forceinline__ unsigned f2bf(float x) {
    unsigned u = __builtin_bit_cast(unsigned, x);
    return (u + 0x7fffu + ((u >> 16) & 1u)) >> 16;
}
__device__ __forceinline__ unsigned pk2(float lo, float hi) {
    return f2bf(lo) | (f2bf(hi) << 16);
}
__device__ __forceinline__ uint4 pk8(const float* p) {
    uint4 r;
    r.x = pk2(p[0], p[1]); r.y = pk2(p[2], p[3]);
    r.z = pk2(p[4], p[5]); r.w = pk2(p[6], p[7]);
    return r;
}
__device__ __forceinline__ uint4 pk8v(float4 a, float4 b) {
    uint4 r;
    r.x = pk2(a.x, a.y); r.y = pk2(a.z, a.w);
    r.z = pk2(b.x, b.y); r.w = pk2(b.z, b.w);
    return r;
}
__device__ __forceinline__ void gll16(const void* g, void* l) {
    __builtin_amdgcn_global_load_lds(
        (const __attribute__((address_space(1))) void*)g,
        (__attribute__((address_space(3))) void*)l, 16, 0, 0);
}

// Fragment-packed A layout (bf16, mfma_f32_16x16x32_bf16 A-operand order):
// uint4 index = ((kc*8 + mt)*4 + ksl)*64 + kg*16 + (row&15)
//   row = mt*16 + (row&15), k = kc*128 + ksl*32 + kg*8 + j (j=0..7)

// ---------------------------------------------------------------------------
// K1: pack rnn_in = [emb(x[b]) | ctxv[b]]  (K=1024) and h0[b]  (K=512)
// ---------------------------------------------------------------------------
__global__ void k_embed_pack(const int* __restrict__ x, const float* __restrict__ ctxv,
                             const float* __restrict__ emb, const float* __restrict__ h0,
                             uint4* __restrict__ apk_rnn, uint4* __restrict__ apk_h0) {
    __shared__ float buf[1024];
    __shared__ float hbuf[512];
    const int b = blockIdx.x, t = threadIdx.x;
    const int row = x[b];
    if (t < 128) {
        ((float4*)buf)[t]  = ((const float4*)(emb + (size_t)row * EMBED))[t];
        ((float4*)hbuf)[t] = ((const float4*)(h0 + (size_t)b * HID))[t];
    } else {
        ((float4*)buf)[t] = ((const float4*)(ctxv + (size_t)b * HID))[t - 128];
    }
    __syncthreads();
    const int mt = b >> 4, lb = b & 15;
    if (t < 128) {                       // rnn frag t (K=1024)
        int kc = t >> 4, ksl = (t >> 2) & 3, kg = t & 3;
        apk_rnn[((kc * 8 + mt) * 4 + ksl) * 64 + kg * 16 + lb] = pk8(&buf[t * 8]);
    } else if (t < 192) {                // h0 frag (K=512)
        int i = t - 128;
        int kc = i >> 4, ksl = (i >> 2) & 3, kg = i & 3;
        apk_h0[((kc * 8 + mt) * 4 + ksl) * 64 + kg * 16 + lb] = pk8(&hbuf[i * 8]);
    }
}

// ---------------------------------------------------------------------------
// K2: 4-wave k-split MFMA GEMM. Block = 16 n-cols, all 128 m; wave w owns
// k-slices [w*K/128, (w+1)*K/128). Partial acc -> LDS -> reduce + epilogue.
// A-fragments read directly from pre-packed global (L2-hot).
// ---------------------------------------------------------------------------
template <int N, int K, int ACT, int HASB, int PACK>
__global__ __launch_bounds__(256, 2) void k_gemm_ks(
        const uint4* __restrict__ apk, const float* __restrict__ W,
        const float* __restrict__ bias, float* __restrict__ C,
        uint4* __restrict__ apk_out) {
    __shared__ float red[4][128][16];          // 32KB
    const int tid = threadIdx.x, lane = tid & 63, wv = tid >> 6;
    const int n0 = blockIdx.x * 16;
    const int ncol = n0 + (lane & 15);
    const int nc = ncol < N ? ncol : N - 1;
    const int kg = lane >> 4;
    constexpr int SPW = K / 128;               // slices per wave (4 or 8)
    f32x4 acc[8];
#pragma unroll
    for (int mt = 0; mt < 8; ++mt) acc[mt] = (f32x4)0.f;
    const float4* W4 = (const float4*)W;
    const size_t wb = (size_t)nc * (K / 4) + kg * 2;
#pragma unroll
    for (int s = 0; s < SPW; ++s) {
        const int ks = wv * SPW + s;
        float4 w0 = W4[wb + ks * 8];
        float4 w1 = W4[wb + ks * 8 + 1];
        short8 bf = __builtin_bit_cast(short8, pk8v(w0, w1));
        const uint4* ap = apk + (((ks >> 2) * 8) * 4 + (ks & 3)) * 64 + lane;
#pragma unroll
        for (int mt = 0; mt < 8; ++mt) {
            short8 af = __builtin_bit_cast(short8, ap[mt * 256]);
            acc[mt] = __builtin_amdgcn_mfma_f32_16x16x32_bf16(af, bf, acc[mt], 0, 0, 0);
        }
    }
#pragma unroll
    for (int mt = 0; mt < 8; ++mt)
#pragma unroll
        for (int j = 0; j < 4; ++j)
            red[wv][mt * 16 + kg * 4 + j][lane & 15] = acc[mt][j];
    __syncthreads();
#pragma unroll
    for (int i = 0; i < 8; ++i) {
        int o = tid + i * 256;
        int r = o >> 4, c = o & 15;
        float v = red[0][r][c] + red[1][r][c] + red[2][r][c] + red[3][r][c];
        if (HASB) v += bias[n0 + c];
        if (ACT) v = tanhf(v);
        C[(size_t)r * N + n0 + c] = v;
        if (PACK) red[0][r][c] = v;            // own (r,c) slot only
    }
    if constexpr (PACK) {
        __syncthreads();
        int r = tid >> 1, hf = tid & 1;        // 256 frags
        float tmp[8];
#pragma unroll
        for (int z = 0; z < 8; ++z) tmp[z] = red[0][r][hf * 8 + z];
        int k0 = n0 + hf * 8;
        int kc = k0 >> 7, ksl = (k0 >> 5) & 3, kg2 = (k0 >> 3) & 3;
        apk_out[((kc * 8 + (r >> 4)) * 4 + ksl) * 64 + kg2 * 16 + (r & 15)] = pk8(tmp);
    }
}

// ---------------------------------------------------------------------------
// K3: GRU gate combine (r,z,n) + pack h fragments (K=512)
// ---------------------------------------------------------------------------
__global__ void k_gru(const float* __restrict__ gi, const float* __restrict__ gh,
                      const float* __restrict__ h0, float* __restrict__ h,
                      uint4* __restrict__ apk_h) {
    __shared__ float hsh[256];
    const int t = threadIdx.x;
    const int idx = blockIdx.x * 256 + t;
    const int b = blockIdx.x >> 1, half = blockIdx.x & 1;
    const int j = half * 256 + t;
    const float* gib = gi + (size_t)b * 1536;
    const float* ghb = gh + (size_t)b * 1536;
    float ir = gib[j], iz = gib[512 + j], inn = gib[1024 + j];
    float hr = ghb[j], hz = ghb[512 + j], hn = ghb[1024 + j];
    float r = 1.f / (1.f + expf(-(ir + hr)));
    float z = 1.f / (1.f + expf(-(iz + hz)));
    float nn = tanhf(inn + r * hn);
    float hv = (1.f - z) * nn + z * h0[idx];
    h[idx] = hv;
    hsh[t] = hv;
    __syncthreads();
    if (t < 32) {
        int k0 = half * 256 + t * 8;
        int kc = k0 >> 7, ksl = (k0 >> 5) & 3, kg = (k0 >> 3) & 3;
        apk_h[((kc * 8 + (b >> 4)) * 4 + ksl) * 64 + kg * 16 + (b & 15)] = pk8(&hsh[t * 8]);
    }
}

// ---------------------------------------------------------------------------
// K4: attention (512 threads)
// ---------------------------------------------------------------------------
__global__ __launch_bounds__(512) void k_attn(const float* __restrict__ enc,
        const float* __restrict__ q, const int* __restrict__ lens,
        const float* __restrict__ h, float* __restrict__ a_out,
        uint4* __restrict__ apk_cat) {
    __shared__ float qs[512];
    __shared__ float red[128];
    __shared__ float aw[128];
    __shared__ float catsh[1024];
    const int b = blockIdx.x, t = threadIdx.x;
    qs[t] = q[(size_t)b * 512 + t];
    __syncthreads();
    const int srow = t >> 2, part = t & 3;
    const float* ep = enc + ((size_t)b * SRC + srow) * 512 + part * 128;
    float s = 0.f;
#pragma unroll
    for (int k4 = 0; k4 < 32; ++k4) {
        float4 e = ((const float4*)ep)[k4];
        float4 qq = *(const float4*)&qs[part * 128 + k4 * 4];
        s = fmaf(e.x, qq.x, fmaf(e.y, qq.y, fmaf(e.z, qq.z, fmaf(e.w, qq.w, s))));
    }
    s += __shfl_xor(s, 1);
    s += __shfl_xor(s, 2);
    if (part == 0) {
        int len = lens[b];
        float val = (srow < len) ? s : 0.f;
        if (val == 0.f) val = -1e10f;   // replicate ref's where(masked==0,-1e10)
        red[srow] = val;
        aw[srow] = val;
    }
    __syncthreads();
    for (int off = 64; off > 0; off >>= 1) {          // max tree
        if (t < off) red[t] = fmaxf(red[t], red[t + off]);
        __syncthreads();
    }
    float mx = red[0];
    __syncthreads();
    if (t < 128) { float e = expf(aw[t] - mx); aw[t] = e; red[t] = e; }
    __syncthreads();
    for (int off = 64; off > 0; off >>= 1) {          // sum tree
        if (t < off) red[t] += red[t + off];
        __syncthreads();
    }
    float denom = red[0];
    if (t < 128) {
        float av = aw[t] / denom;
        aw[t] = av;
        a_out[(size_t)t * B + b] = av;                // layout [S][B]
    }
    __syncthreads();
    float a0 = 0.f;
    const float* e2 = enc + (size_t)b * (SRC * 512) + t;
#pragma unroll 4
    for (int s2 = 0; s2 < SRC; ++s2) a0 = fmaf(aw[s2], e2[(size_t)s2 * 512], a0);
    catsh[t] = a0;
    catsh[512 + t] = h[(size_t)b * 512 + t];
    __syncthreads();
    if (t < 128) {                                    // pack cat frag (K=1024)
        int kc = t >> 4, ksl = (t >> 2) & 3, kg = t & 3;
        apk_cat[((kc * 8 + (b >> 4)) * 4 + ksl) * 64 + kg * 16 + (b & 15)] =
            pk8(&catsh[t * 8]);
    }
}

// ---------------------------------------------------------------------------
// K5: fc1 persistent GEMM. 256 blocks x 8 waves; A (128KB packed bf16) staged
// in LDS ONCE via global_load_lds; grid-stride over 393 tiles of 128 cols.
// Per tile per wave: burst-load all 32 W-float4 (full K=512) into registers,
// consume with 16 k-slices x 8 MFMA; fused per-tile LSE partials.
// ---------------------------------------------------------------------------
__global__ __launch_bounds__(512, 2) void k_fc1p(
        const uint4* __restrict__ apk, const float* __restrict__ W,
        const float* __restrict__ bias, float* __restrict__ C,
        float2* __restrict__ pout) {
    __shared__ uint4 As[8192];                 // 128KB: ALL of packed A
    __shared__ float pm8[8][128], ps8[8][128]; // per-wave row LSE partials
    const int tid = threadIdx.x, lane = tid & 63, wv = tid >> 6;
    const int kg = lane >> 4;
#pragma unroll
    for (int it = 0; it < 16; ++it)            // stage A once
        gll16(apk + it * 512 + tid, As + it * 512 + tid);
    __syncthreads();
    const float4* W4 = (const float4*)W;

    for (int nt = blockIdx.x; nt < NT393; nt += 256) {
        const int ncol = nt * 128 + wv * 16 + (lane & 15);
        const bool valid = ncol < VOCAB;
        const int nc = valid ? ncol : VOCAB - 1;
        const size_t wb = (size_t)nc * 128 + kg * 2;
        f32x4 acc[8];
#pragma unroll
        for (int mt = 0; mt < 8; ++mt) acc[mt] = (f32x4)0.f;
        float4 wr[32];
#pragma unroll
        for (int i = 0; i < 16; ++i) {         // burst: full-K W for own col
            wr[2 * i]     = W4[wb + (size_t)i * 8];
            wr[2 * i + 1] = W4[wb + (size_t)i * 8 + 1];
        }
#pragma unroll
        for (int ks = 0; ks < 16; ++ks) {
            short8 bf = __builtin_bit_cast(short8, pk8v(wr[2 * ks], wr[2 * ks + 1]));
            const int base = ((ks >> 2) * 32 + (ks & 3)) * 64 + lane;
#pragma unroll
            for (int mt = 0; mt < 8; ++mt) {
                short8 af = __builtin_bit_cast(short8, As[base + mt * 256]);
                acc[mt] = __builtin_amdgcn_mfma_f32_16x16x32_bf16(af, bf, acc[mt], 0, 0, 0);
            }
        }
        float bb = bias[nc];
#pragma unroll
        for (int mt = 0; mt < 8; ++mt) {
#pragma unroll
            for (int j = 0; j < 4; ++j) {
                float v = acc[mt][j] + bb;
                int row = mt * 16 + kg * 4 + j;
                if (valid) C[(size_t)row * VOCAB + ncol] = v;
                float val = valid ? v : -1e30f;
                float m16 = val;
                m16 = fmaxf(m16, __shfl_xor(m16, 1));
                m16 = fmaxf(m16, __shfl_xor(m16, 2));
                m16 = fmaxf(m16, __shfl_xor(m16, 4));
                m16 = fmaxf(m16, __shfl_xor(m16, 8));
                float e = valid ? __expf(val - m16) : 0.f;
                e += __shfl_xor(e, 1);
                e += __shfl_xor(e, 2);
                e += __shfl_xor(e, 4);
                e += __shfl_xor(e, 8);
                if ((lane & 15) == 0) { pm8[wv][row] = m16; ps8[wv][row] = e; }
            }
        }
        __syncthreads();
        if (tid < 128) {
            float m = pm8[0][tid], s = ps8[0][tid];
#pragma unroll
            for (int w = 1; w < 8; ++w) {
                float m2 = pm8[w][tid], s2 = ps8[w][tid];
                float mm = fmaxf(m, m2);
                s = s * __expf(m - mm) + s2 * __expf(m2 - mm);
                m = mm;
            }
            pout[(size_t)tid * NT393 + nt] = make_float2(m, s);
        }
        __syncthreads();                       // pm8/ps8 reusable next tile
    }
}

// ---------------------------------------------------------------------------
// K6a: merge per-tile LSE partials -> L[row]
// ---------------------------------------------------------------------------
__global__ __launch_bounds__(256) void k_lse_final(const float2* __restrict__ pout,
                                                   float* __restrict__ L, int nblk) {
    const int row = blockIdx.x, t = threadIdx.x;
    float m = -1e30f, s = 0.f;
    for (int i = t; i < nblk; i += 256) {
        float2 p = pout[(size_t)row * nblk + i];
        float mm = fmaxf(m, p.x);
        s = s * __expf(m - mm) + p.y * __expf(p.x - mm);
        m = mm;
    }
    __shared__ float sm[256], ss[256];
    sm[t] = m; ss[t] = s; __syncthreads();
    for (int off = 128; off > 0; off >>= 1) {
        if (t < off) {
            float m2 = sm[t + off], s2 = ss[t + off];
            float mm = fmaxf(sm[t], m2);
            ss[t] = ss[t] * __expf(sm[t] - mm) + s2 * __expf(m2 - mm);
            sm[t] = mm;
        }
        __syncthreads();
    }
    if (t == 0) L[row] = sm[0] + logf(ss[0]);
}

// ---------------------------------------------------------------------------
// K6b: log_probs = logits - L[b]  (in place), full-machine grid
// ---------------------------------------------------------------------------
__global__ __launch_bounds__(512) void k_lsub(float* __restrict__ logits,
                                              const float* __restrict__ L) {
    const int b = blockIdx.y;
    const float l = L[b];
    float* row = logits + (size_t)b * VOCAB;
    int c0 = (blockIdx.x * 512 + threadIdx.x) * 4;
    if (c0 + 4 <= VOCAB) {
        float4 x = *(float4*)(row + c0);
        x.x -= l; x.y -= l; x.z -= l; x.w -= l;
        *(float4*)(row + c0) = x;
    } else {
        for (int c = c0; c < VOCAB; ++c) row[c] -= l;
    }
}

// ---------------------------------------------------------------------------
// K6-fallback: fused log-softmax (online LSE + in-place subtract)
// ---------------------------------------------------------------------------
__global__ __launch_bounds__(1024) void k_lse_sub(float* __restrict__ logits) {
    const int b = blockIdx.x, t = threadIdx.x;
    float* row = logits + (size_t)b * VOCAB;
    const int N4 = VOCAB >> 2;
    float m = -1e30f, s = 0.f;
    for (int i = t; i < N4; i += 1024) {
        float4 x = ((const float4*)row)[i];
        float xs[4] = {x.x, x.y, x.z, x.w};
#pragma unroll
        for (int j = 0; j < 4; ++j) {
            float v = xs[j];
            if (v > m) { s = s * __expf(m - v) + 1.f; m = v; }
            else        s += __expf(v - m);
        }
    }
    if (t == 0) {
        float v = row[VOCAB - 1];
        if (v > m) { s = s * __expf(m - v) + 1.f; m = v; }
        else        s += __expf(v - m);
    }
    __shared__ float sm[1024], ss[1024];
    sm[t] = m; ss[t] = s;
    __syncthreads();
    for (int off = 512; off > 0; off >>= 1) {
        if (t < off) {
            float m2 = sm[t + off], s2 = ss[t + off];
            float mm = fmaxf(sm[t], m2);
            ss[t] = ss[t] * __expf(sm[t] - mm) + s2 * __expf(m2 - mm);
            sm[t] = mm;
        }
        __syncthreads();
    }
    __shared__ float Lsh;
    if (t == 0) Lsh = sm[0] + logf(ss[0]);
    __syncthreads();
    float L = Lsh;
    for (int i = t; i < N4; i += 1024) {
        float4 x = ((const float4*)row)[i];
        x.x -= L; x.y -= L; x.z -= L; x.w -= L;
        ((float4*)row)[i] = x;
    }
    if (t == 0) row[VOCAB - 1] -= L;
}

// ---------------------------------------------------------------------------
extern "C" void kernel_launch(void* const* d_in, const int* in_sizes, int n_in,
                              void* d_out, int out_size, void* d_ws, size_t ws_size,
                              hipStream_t stream) {
    const int*   x    = (const int*)d_in[0];
    const float* h0   = (const float*)d_in[1];   // decoder_hidden [1,B,H]
    const int*   lens = (const int*)d_in[2];
    const float* enc  = (const float*)d_in[3];   // [B,SRC,H]
    const float* ctxv = (const float*)d_in[4];   // [B,H]
    const float* emb  = (const float*)d_in[5];   // [V,E]
    const float* wih  = (const float*)d_in[6];   // [1536,1024]
    const float* whh  = (const float*)d_in[7];   // [1536,512]
    const float* bih  = (const float*)d_in[8];
    const float* bhh  = (const float*)d_in[9];
    const float* Wa   = (const float*)d_in[10];  // [512,512]
    const float* Wc   = (const float*)d_in[11];  // [512,1024]
    const float* fc1w = (const float*)d_in[12];  // [V,512]
    const float* fc1b = (const float*)d_in[13];

    float* out     = (float*)d_out;
    float* outLogp = out;                                  // [B][VOCAB]
    float* outHid  = out + (size_t)B * VOCAB;              // [B][HID]
    float* outA    = outHid + (size_t)B * HID;             // [SRC][B]
    float* outCtx  = outA + (size_t)SRC * B;               // [B][HID]

    // scratch inside the not-yet-written log_probs region (6.43M floats)
    float* gi = outLogp;                                   // [B][1536]
    float* gh = gi + B * 1536;                             // [B][1536]
    float* q  = gh + B * 1536;                             // [B][512]
    uint4* apk_rnn = (uint4*)(q + B * HID);                // 16384 u4 (K=1024)
    uint4* apk_h0  = apk_rnn + 16384;                      // 8192  u4 (K=512)
    uint4* apk_h   = apk_h0 + 8192;                        // 8192  u4 (K=512)
    uint4* apk_cat = apk_h + 8192;                         // 16384 u4 (K=1024)

    uint4*  apk_ctx = (uint4*)d_ws;                        // 128KB (survives fc1)
    size_t  off_pout = 131072;
    size_t  off_L    = off_pout + (size_t)B * NT393 * sizeof(float2);
    bool bigws = ws_size >= off_L + 512;
    float2* pout = bigws ? (float2*)((char*)d_ws + off_pout) : nullptr;
    float*  Lb   = bigws ? (float*)((char*)d_ws + off_L) : nullptr;

    k_embed_pack<<<dim3(B), dim3(256), 0, stream>>>(x, ctxv, emb, h0, apk_rnn, apk_h0);
    k_gemm_ks<1536, 1024, 0, 1, 0><<<dim3(96), dim3(256), 0, stream>>>(
        apk_rnn, wih, bih, gi, nullptr);
    k_gemm_ks<1536, 512, 0, 1, 0><<<dim3(96), dim3(256), 0, stream>>>(
        apk_h0, whh, bhh, gh, nullptr);
    k_gru<<<dim3(256), dim3(256), 0, stream>>>(gi, gh, h0, outHid, apk_h);
    k_gemm_ks<512, 512, 0, 0, 0><<<dim3(32), dim3(256), 0, stream>>>(
        apk_h, Wa, nullptr, q, nullptr);
    k_attn<<<dim3(B), dim3(512), 0, stream>>>(enc, q, lens, outHid, outA, apk_cat);
    k_gemm_ks<512, 1024, 1, 0, 1><<<dim3(32), dim3(256), 0, stream>>>(
        apk_cat, Wc, nullptr, outCtx, apk_ctx);
    if (bigws) {
        k_fc1p<<<dim3(256), dim3(512), 0, stream>>>(apk_ctx, fc1w, fc1b, outLogp, pout);
        k_lse_final<<<dim3(B), dim3(256), 0, stream>>>(pout, Lb, NT393);
        k_lsub<<<dim3(25, B), dim3(512), 0, stream>>>(outLogp, Lb);
    } else {
        k_fc1p<<<dim3(256), dim3(512), 0, stream>>>(apk_ctx, fc1w, fc1b, outLogp, nullptr);
        k_lse_sub<<<dim3(B), dim3(1024), 0, stream>>>(outLogp);
    }
}